// Round 4
// baseline (1985.648 us; speedup 1.0000x reference)
//
#include <hip/hip_runtime.h>
#include <hip/hip_bf16.h>
#include <stdint.h>

#define SEQ   2048
#define DIN   5
#define HID   64
#define DTC   0.1f
#define NW    4
#define GT    4           // batch tiles (16 cols each) per wave
#define COLS  (16*GT)     // 64 batch cols per block

typedef __attribute__((ext_vector_type(8))) __bf16  bf16x8;
typedef __attribute__((ext_vector_type(8))) short   short8;
typedef __attribute__((ext_vector_type(4))) float   f32x4;
typedef __attribute__((ext_vector_type(4))) int     i32x4;
typedef __attribute__((ext_vector_type(2))) int     i32x2;
typedef unsigned long long u64;

__device__ __forceinline__ unsigned short f2bf(float f) {
    unsigned int u = __builtin_bit_cast(unsigned int, f);
    return (unsigned short)((u + 0x7FFFu + ((u >> 16) & 1u)) >> 16);  // RNE
}

__device__ __forceinline__ float fast_tanh(float x) {
    float e = __expf(2.0f * x);                       // saturates correctly at +-1
    return 1.0f - 2.0f * __builtin_amdgcn_rcpf(e + 1.0f);
}

__device__ __forceinline__ unsigned int cvt_pk_bf16(float lo, float hi) {
    unsigned int r;
    asm("v_cvt_pk_bf16_f32 %0, %1, %2" : "=v"(r) : "v"(lo), "v"(hi));
    return r;
}

// 4 waves; wave w owns hidden rows [16w,16w+16) for GT=4 independent 16-col
// batch tiles (weights/A-fragments shared). tanh exchange per tile via
// double-buffered fragment-linear LDS (reads at lane*16, conflict-free).
// One barrier per step covers all tiles; 4 independent chains give ILP that
// fills the barrier/LDS/MFMA latency window.
__global__ __launch_bounds__(256) void ltc_kernel(
    const float* __restrict__ x,
    const float* __restrict__ tau,
    const float* __restrict__ Wih,
    const float* __restrict__ bih,
    const float* __restrict__ Whh,
    const float* __restrict__ bhh,
    const float* __restrict__ outw,
    const float* __restrict__ outb,
    float* __restrict__ out)
{
    const int tid  = threadIdx.x;
    const int wave = tid >> 6;
    const int lane = tid & 63;
    const int lg   = lane >> 4;
    const int ln   = lane & 15;
    const int b0   = blockIdx.x * COLS;

    __shared__ __align__(16) unsigned short sbuf[2][GT][1024];  // 2 x GT x 2KB
    __shared__ float redbuf[GT][NW][4][16];

    const int jbase = 16 * wave + 4 * lg;
    const int arow  = 16 * wave + ln;

    float a[4], ow[4];
#pragma unroll
    for (int r = 0; r < 4; ++r) {
        a[r]  = 1.0f - DTC / fabsf(tau[jbase + r]);
        ow[r] = outw[jbase + r];
    }

    // A fragments (verified layout; shared across the GT tiles)
    short8 s0 = {0,0,0,0,0,0,0,0}, s1 = {0,0,0,0,0,0,0,0}, s2 = {0,0,0,0,0,0,0,0};
#pragma unroll
    for (int q = 0; q < 8; ++q) {
        s0[q] = (short)f2bf(DTC * Whh[arow * HID + lg * 8 + q]);
        s1[q] = (short)f2bf(DTC * Whh[arow * HID + 32 + lg * 8 + q]);
    }
    if (lg == 0) {
#pragma unroll
        for (int d = 0; d < DIN; ++d) s2[d] = (short)f2bf(DTC * Wih[arow * DIN + d]);
        s2[5] = (short)f2bf(DTC * (bih[arow] + bhh[arow]));
    }
    const bf16x8 Ahh0 = __builtin_bit_cast(bf16x8, s0);
    const bf16x8 Ahh1 = __builtin_bit_cast(bf16x8, s1);
    const bf16x8 Aix  = __builtin_bit_cast(bf16x8, s2);

    // write slot: rows jbase..jbase+3, col ln -> reader-fragment-linear address
    const int wbyte = ((jbase >= 32) ? 1024 : 0) + (((jbase & 31) >> 3) * 256)
                    + ln * 16 + (((jbase >> 2) & 1) * 8);

    // zero parity-1 buffers (read at t=0): GT*2KB = GT*256 u64
#pragma unroll
    for (int i = 0; i < GT; ++i) ((u64*)sbuf[1])[tid + 256 * i] = 0ULL;

    const float* xp[GT];
    float ex[GT][DIN], ox[GT][DIN];
#pragma unroll
    for (int g = 0; g < GT; ++g) {
        xp[g] = x + (size_t)(b0 + 16 * g + ln) * (SEQ * DIN);
#pragma unroll
        for (int d = 0; d < DIN; ++d) { ex[g][d] = xp[g][d]; ox[g][d] = xp[g][DIN + d]; }
    }

    f32x4 h[GT];
#pragma unroll
    for (int g = 0; g < GT; ++g) { h[g][0]=0.f; h[g][1]=0.f; h[g][2]=0.f; h[g][3]=0.f; }

    int xoff = 2 * DIN;   // uniform: next prefetch element offset (t+2)

#define STEP(PAR, PX, PF, XADD)                                                      \
    {                                                                                \
        __syncthreads();                                                             \
        i32x4 r0[GT], r1[GT];                                                        \
        _Pragma("unroll")                                                            \
        for (int g = 0; g < GT; ++g) {                                               \
            const char* rb = (const char*)sbuf + ((PAR) ^ 1) * 8192 + g * 2048 + lane * 16; \
            r0[g] = *(const i32x4*)rb;                                               \
            r1[g] = *(const i32x4*)(rb + 1024);                                      \
        }                                                                            \
        i32x4 bx[GT];                                                                \
        _Pragma("unroll")                                                            \
        for (int g = 0; g < GT; ++g) {                                               \
            bx[g][0] = (int)cvt_pk_bf16(PX[g][0], PX[g][1]);                         \
            bx[g][1] = (int)cvt_pk_bf16(PX[g][2], PX[g][3]);                         \
            bx[g][2] = (int)cvt_pk_bf16(PX[g][4], 1.0f);                             \
            bx[g][3] = 0;                                                            \
        }                                                                            \
        if (PF) {                                                                    \
            _Pragma("unroll")                                                        \
            for (int g = 0; g < GT; ++g)                                             \
                _Pragma("unroll")                                                    \
                for (int d = 0; d < DIN; ++d) PX[g][d] = xp[g][xoff + (XADD) + d];   \
        }                                                                            \
        _Pragma("unroll")                                                            \
        for (int g = 0; g < GT; ++g) {                                               \
            f32x4 c;                                                                 \
            c[0] = a[0]*h[g][0]; c[1] = a[1]*h[g][1];                                \
            c[2] = a[2]*h[g][2]; c[3] = a[3]*h[g][3];                                \
            c = __builtin_amdgcn_mfma_f32_16x16x32_bf16(Aix,  __builtin_bit_cast(bf16x8, bx[g]), c, 0, 0, 0); \
            c = __builtin_amdgcn_mfma_f32_16x16x32_bf16(Ahh0, __builtin_bit_cast(bf16x8, r0[g]), c, 0, 0, 0); \
            c = __builtin_amdgcn_mfma_f32_16x16x32_bf16(Ahh1, __builtin_bit_cast(bf16x8, r1[g]), c, 0, 0, 0); \
            h[g] = c;                                                                \
            float t0 = fast_tanh(c[0]), t1 = fast_tanh(c[1]);                        \
            float t2 = fast_tanh(c[2]), t3 = fast_tanh(c[3]);                        \
            i32x2 w; w[0] = (int)cvt_pk_bf16(t0, t1); w[1] = (int)cvt_pk_bf16(t2, t3); \
            *(i32x2*)((char*)sbuf + (PAR) * 8192 + g * 2048 + wbyte) = w;            \
        }                                                                            \
    }

    for (int t = 0; t < SEQ - 2; t += 2) {
        STEP(0, ex, true, 0)
        STEP(1, ox, true, DIN)
        xoff += 2 * DIN;
    }
    STEP(0, ex, false, 0)   // t = SEQ-2
    STEP(1, ox, false, 0)   // t = SEQ-1
#undef STEP

    // epilogue: out[b] = tanh(h_final) . out_w + out_b
#pragma unroll
    for (int g = 0; g < GT; ++g) {
        float part = fast_tanh(h[g][0]) * ow[0] + fast_tanh(h[g][1]) * ow[1]
                   + fast_tanh(h[g][2]) * ow[2] + fast_tanh(h[g][3]) * ow[3];
        redbuf[g][wave][lg][ln] = part;
    }
    __syncthreads();
    if (tid < COLS) {
        const int g = tid >> 4, c = tid & 15;
        float s = outb[0];
#pragma unroll
        for (int w = 0; w < NW; ++w)
#pragma unroll
            for (int l = 0; l < 4; ++l) s += redbuf[g][w][l][c];
        out[b0 + tid] = s;
    }
}

extern "C" void kernel_launch(void* const* d_in, const int* in_sizes, int n_in,
                              void* d_out, int out_size, void* d_ws, size_t ws_size,
                              hipStream_t stream) {
    const float* x    = (const float*)d_in[0];
    const float* tau  = (const float*)d_in[1];
    const float* Wih  = (const float*)d_in[2];
    const float* bih  = (const float*)d_in[3];
    const float* Whh  = (const float*)d_in[4];
    const float* bhh  = (const float*)d_in[5];
    const float* outw = (const float*)d_in[6];
    const float* outb = (const float*)d_in[7];
    float* out = (float*)d_out;

    const int batch = in_sizes[0] / (SEQ * DIN);   // 4096
    ltc_kernel<<<batch / COLS, NW * 64, 0, stream>>>(x, tau, Wih, bih, Whh, bhh, outw, outb, out);
}

// Round 7
// 889.611 us; speedup vs baseline: 2.2320x; 2.2320x over previous
//
#include <hip/hip_runtime.h>
#include <hip/hip_bf16.h>
#include <stdint.h>

#define SEQ   2048
#define DIN   5
#define HID   64
#define DTC   0.1f
#define NGRP  2        // independent 4-wave tile groups per block
#define NW4   4        // waves per group

typedef __attribute__((ext_vector_type(8))) __bf16  bf16x8;
typedef __attribute__((ext_vector_type(8))) short   short8;
typedef __attribute__((ext_vector_type(4))) float   f32x4;
typedef __attribute__((ext_vector_type(4))) int     i32x4;
typedef __attribute__((ext_vector_type(2))) int     i32x2;
typedef unsigned long long u64;

__device__ __forceinline__ unsigned short f2bf(float f) {
    unsigned int u = __builtin_bit_cast(unsigned int, f);
    return (unsigned short)((u + 0x7FFFu + ((u >> 16) & 1u)) >> 16);  // RNE
}

__device__ __forceinline__ float fast_tanh(float x) {
    float e = __expf(2.0f * x);                       // saturates correctly at +-1
    return 1.0f - 2.0f * __builtin_amdgcn_rcpf(e + 1.0f);
}

__device__ __forceinline__ unsigned int cvt_pk_bf16(float lo, float hi) {
    unsigned int r;
    asm("v_cvt_pk_bf16_f32 %0, %1, %2" : "=v"(r) : "v"(lo), "v"(hi));
    return r;
}

// 8 waves = 2 independent 4-wave groups, each running one 16-col batch tile
// with the r3/r4-VERIFIED step body (barrier at top; conflict-free
// fragment-linear LDS exchange; per-value tanh; single u64 write).
// 2 waves/SIMD: the second group's issue stream fills the first's
// barrier/LDS/MFMA latency windows.
__global__ __launch_bounds__(512) void ltc_kernel(
    const float* __restrict__ x,
    const float* __restrict__ tau,
    const float* __restrict__ Wih,
    const float* __restrict__ bih,
    const float* __restrict__ Whh,
    const float* __restrict__ bhh,
    const float* __restrict__ outw,
    const float* __restrict__ outb,
    float* __restrict__ out)
{
    const int tid  = threadIdx.x;
    const int wave = tid >> 6;
    const int lane = tid & 63;
    const int g2   = wave >> 2;   // tile group 0/1
    const int w4   = wave & 3;    // wave within group
    const int lg   = lane >> 4;
    const int ln   = lane & 15;
    const int b0   = blockIdx.x * (16 * NGRP) + g2 * 16;

    __shared__ __align__(16) unsigned short sbuf[NGRP][2][1024];  // [grp][parity][frag]
    __shared__ float redbuf[NGRP][NW4][4][16];

    const int jbase = 16 * w4 + 4 * lg;   // first C/D row (hidden idx) of this lane
    const int arow  = 16 * w4 + ln;       // A-fragment row (hidden idx)

    float a[4], ow[4];
#pragma unroll
    for (int r = 0; r < 4; ++r) {
        a[r]  = 1.0f - DTC / fabsf(tau[jbase + r]);
        ow[r] = outw[jbase + r];
    }

    // A fragments: lane l holds A[l&15][(l>>4)*8 + q]  (verified r2/r3/r4)
    short8 s0 = {0,0,0,0,0,0,0,0}, s1 = {0,0,0,0,0,0,0,0}, s2 = {0,0,0,0,0,0,0,0};
#pragma unroll
    for (int q = 0; q < 8; ++q) {
        s0[q] = (short)f2bf(DTC * Whh[arow * HID + lg * 8 + q]);
        s1[q] = (short)f2bf(DTC * Whh[arow * HID + 32 + lg * 8 + q]);
    }
    if (lg == 0) {
#pragma unroll
        for (int d = 0; d < DIN; ++d) s2[d] = (short)f2bf(DTC * Wih[arow * DIN + d]);
        s2[5] = (short)f2bf(DTC * (bih[arow] + bhh[arow]));
    }
    const bf16x8 Ahh0 = __builtin_bit_cast(bf16x8, s0);
    const bf16x8 Ahh1 = __builtin_bit_cast(bf16x8, s1);
    const bf16x8 Aix  = __builtin_bit_cast(bf16x8, s2);

    // write slot (fragment-linear): rows jbase..jbase+3, col ln
    const int wbyte = ((jbase >= 32) ? 1024 : 0) + (((jbase & 31) >> 3) * 256)
                    + ln * 16 + (((jbase >> 2) & 1) * 8);
    char* const wp0 = (char*)&sbuf[g2][0][0] + wbyte;
    char* const wp1 = (char*)&sbuf[g2][1][0] + wbyte;
    const char* const rp0 = (const char*)&sbuf[g2][0][0] + lane * 16;
    const char* const rp1 = (const char*)&sbuf[g2][1][0] + lane * 16;

    // zero parity-1 buffer of this group (read at t=0): 256 u64, all 4 waves
    ((u64*)&sbuf[g2][1][0])[w4 * 64 + lane] = 0ULL;

    // depth-2 x prefetch (lanes lg!=0 read same addrs -> broadcast; unused there)
    const float* xb = x + (size_t)(b0 + ln) * (SEQ * DIN);
    float ex[DIN], ox[DIN];
#pragma unroll
    for (int d = 0; d < DIN; ++d) { ex[d] = xb[d]; ox[d] = xb[DIN + d]; }
    const float* xnext = xb + 2 * DIN;   // -> x[t+2]

    f32x4 h = {0.f, 0.f, 0.f, 0.f};

    // r3/r4-verified step body, transplanted verbatim (barrier at top)
#define STEP(PAR, PX, PF, XADD)                                                    \
    {                                                                              \
        __syncthreads();                                                           \
        const char* rb = (PAR) ? rp0 : rp1;        /* read parity = !PAR */        \
        i32x4 r0 = *(const i32x4*)(rb);                                            \
        i32x4 r1 = *(const i32x4*)(rb + 1024);                                     \
        i32x4 bx;                                                                  \
        bx[0] = (int)cvt_pk_bf16(PX[0], PX[1]);                                    \
        bx[1] = (int)cvt_pk_bf16(PX[2], PX[3]);                                    \
        bx[2] = (int)cvt_pk_bf16(PX[4], 1.0f);                                     \
        bx[3] = 0;                                                                 \
        if (PF) {                                                                  \
            _Pragma("unroll")                                                      \
            for (int d = 0; d < DIN; ++d) PX[d] = xnext[(XADD) + d];               \
        }                                                                          \
        f32x4 c;                                                                   \
        c[0] = a[0]*h[0]; c[1] = a[1]*h[1]; c[2] = a[2]*h[2]; c[3] = a[3]*h[3];    \
        c = __builtin_amdgcn_mfma_f32_16x16x32_bf16(Aix,  __builtin_bit_cast(bf16x8, bx), c, 0, 0, 0); \
        c = __builtin_amdgcn_mfma_f32_16x16x32_bf16(Ahh0, __builtin_bit_cast(bf16x8, r0), c, 0, 0, 0); \
        c = __builtin_amdgcn_mfma_f32_16x16x32_bf16(Ahh1, __builtin_bit_cast(bf16x8, r1), c, 0, 0, 0); \
        h = c;                                                                     \
        float t0 = fast_tanh(c[0]), t1 = fast_tanh(c[1]);                          \
        float t2 = fast_tanh(c[2]), t3 = fast_tanh(c[3]);                          \
        i32x2 w; w[0] = (int)cvt_pk_bf16(t0, t1); w[1] = (int)cvt_pk_bf16(t2, t3); \
        *(i32x2*)((PAR) ? wp1 : wp0) = w;                                          \
    }

    for (int t = 0; t < SEQ - 2; t += 2) {
        STEP(0, ex, true, 0)
        STEP(1, ox, true, DIN)
        xnext += 2 * DIN;
    }
    STEP(0, ex, false, 0)   // t = SEQ-2
    STEP(1, ox, false, 0)   // t = SEQ-1
#undef STEP

    // epilogue: out[b] = tanh(h_final) . out_w + out_b
    float part = fast_tanh(h[0]) * ow[0] + fast_tanh(h[1]) * ow[1]
               + fast_tanh(h[2]) * ow[2] + fast_tanh(h[3]) * ow[3];
    redbuf[g2][w4][lg][ln] = part;
    __syncthreads();
    if (tid < 16 * NGRP) {
        const int g = tid >> 4, cix = tid & 15;
        float s = outb[0];
#pragma unroll
        for (int w = 0; w < NW4; ++w)
#pragma unroll
            for (int l = 0; l < 4; ++l) s += redbuf[g][w][l][cix];
        out[blockIdx.x * (16 * NGRP) + tid] = s;
    }
}

extern "C" void kernel_launch(void* const* d_in, const int* in_sizes, int n_in,
                              void* d_out, int out_size, void* d_ws, size_t ws_size,
                              hipStream_t stream) {
    const float* x    = (const float*)d_in[0];
    const float* tau  = (const float*)d_in[1];
    const float* Wih  = (const float*)d_in[2];
    const float* bih  = (const float*)d_in[3];
    const float* Whh  = (const float*)d_in[4];
    const float* bhh  = (const float*)d_in[5];
    const float* outw = (const float*)d_in[6];
    const float* outb = (const float*)d_in[7];
    float* out = (float*)d_out;

    const int batch = in_sizes[0] / (SEQ * DIN);   // 4096
    ltc_kernel<<<batch / (16 * NGRP), 512, 0, stream>>>(x, tau, Wih, bih, Whh, bhh, outw, outb, out);
}